// Round 1
// baseline (415.746 us; speedup 1.0000x reference)
//
#include <hip/hip_runtime.h>
#include <hip/hip_bf16.h>
#include <math.h>

#define D_MODEL 32
#define N_HEADS 4
#define DHEAD   8
#define S_LEN   2048
#define B_SZ    8
#define LN_EPS  1e-5f
#define MASK_FILL -1.0e9f
#define LOG2E   1.44269504088896340736f
#define QK_SCALE 0.35355339059327373f   /* 1/sqrt(8) */

#define QT   16      /* q rows per block (x4 heads = 64 threads) */
#define CK   64      /* k-chunk staged in LDS */
#define MPAD 65      /* mask LDS row pad: bank = (ql+k)%32, conflict-free */

// ---------------------------------------------------------------------------
// Mask dtype probe: bool arrays may arrive as 1-byte or as int32 (0/1).
// If int32, bytes at offsets 1,2,3 (mod 4) of the first 64 words are all 0.
// For random 0/1 bytes the chance of that is 2^-192 => reliable detector.
__global__ void detect_mask_dtype(const unsigned char* __restrict__ mb,
                                  int* __restrict__ flag) {
    int t = threadIdx.x;  // 64 lanes
    unsigned char b1 = mb[t * 4 + 1];
    unsigned char b2 = mb[t * 4 + 2];
    unsigned char b3 = mb[t * 4 + 3];
    int ok = ((b1 | b2 | b3) == 0);
    unsigned long long vote = __ballot(ok);
    if (t == 0) flag[0] = (vote == ~0ULL) ? 1 : 0;   // 1 => int32 layout
}

// ---------------------------------------------------------------------------
// QKV projection: out = (x @ W + b) * scale.  Q gets 1/sqrt(8)*log2(e) folded
// in so the attention kernel can run softmax in exp2 domain.
__global__ __launch_bounds__(256) void proj_kernel(
    const float* __restrict__ xQ, const float* __restrict__ xK,
    const float* __restrict__ xV,
    const float* __restrict__ WQ, const float* __restrict__ bQ,
    const float* __restrict__ WK, const float* __restrict__ bK,
    const float* __restrict__ WV, const float* __restrict__ bV,
    float* __restrict__ Qs, float* __restrict__ Ks, float* __restrict__ Vs)
{
    const float* x; const float* W; const float* bias; float* dst; float scale;
    if (blockIdx.y == 0)      { x = xQ; W = WQ; bias = bQ; dst = Qs; scale = QK_SCALE * LOG2E; }
    else if (blockIdx.y == 1) { x = xK; W = WK; bias = bK; dst = Ks; scale = 1.0f; }
    else                      { x = xV; W = WV; bias = bV; dst = Vs; scale = 1.0f; }

    __shared__ float xs[8][32];
    __shared__ float Ws[32][32];
    int t = threadIdx.x;
    long base = (long)blockIdx.x * 256;    // 8 rows x 32 cols
    xs[t >> 5][t & 31] = x[base + t];
#pragma unroll
    for (int i = 0; i < 4; ++i) {
        int f = i * 256 + t;
        Ws[f >> 5][f & 31] = W[f];
    }
    __syncthreads();
    int r = t >> 5, j = t & 31;
    float acc = bias[j];
#pragma unroll
    for (int i = 0; i < 32; ++i) acc = fmaf(xs[r][i], Ws[i][j], acc);
    dst[base + t] = acc * scale;
}

// ---------------------------------------------------------------------------
// Flash attention: 1 wave per block; thread t owns (q = q0 + t/4, head = t&3).
// Online softmax in exp2 domain (Q pre-scaled by 1/sqrt(8)*log2e).
__global__ __launch_bounds__(64) void attn_kernel(
    const float* __restrict__ Qs, const float* __restrict__ Ks,
    const float* __restrict__ Vs, const void* __restrict__ mask,
    const int* __restrict__ flag_p, float* __restrict__ sa_out)
{
    __shared__ float Kch[CK * 32];
    __shared__ float Vch[CK * 32];
    __shared__ int   mch[QT * MPAD];

    int t   = threadIdx.x;
    int bid = blockIdx.x;
    int b   = bid >> 7;             // S/QT = 128 tiles per batch
    int q0  = (bid & 127) << 4;
    int ql  = t >> 2, h = t & 3;
    long qrow = (long)b * S_LEN + q0 + ql;

    float4 qa = *(const float4*)(Qs + qrow * 32 + h * 8);
    float4 qb = *(const float4*)(Qs + qrow * 32 + h * 8 + 4);

    int is_i32 = flag_p[0];
    const int* m32           = (const int*)mask;
    const unsigned char* m8  = (const unsigned char*)mask;
    long mbase = ((long)b * S_LEN + q0) * S_LEN;

    float m = -INFINITY, l = 0.f;
    float c0=0,c1=0,c2=0,c3=0,c4=0,c5=0,c6=0,c7=0;

    const float4* Kg = (const float4*)(Ks + (long)b * S_LEN * 32);
    const float4* Vg = (const float4*)(Vs + (long)b * S_LEN * 32);

    for (int kc = 0; kc < S_LEN; kc += CK) {
        // stage K,V chunk: CK*32 floats = 512 float4 each
#pragma unroll
        for (int i = 0; i < 8; ++i) {
            int f = t + i * 64;
            ((float4*)Kch)[f] = Kg[kc * 8 + f];
            ((float4*)Vch)[f] = Vg[kc * 8 + f];
        }
        // stage mask chunk: QT x CK
#pragma unroll
        for (int i = 0; i < 16; ++i) {
            int idx = t + i * 64;
            int qi = idx >> 6, kk = idx & 63;
            long gi = mbase + (long)qi * S_LEN + kc + kk;
            int mv = is_i32 ? m32[gi] : (int)m8[gi];
            mch[qi * MPAD + kk] = mv;
        }
        __syncthreads();
#pragma unroll 4
        for (int k = 0; k < CK; ++k) {
            const float* Kr = Kch + k * 32 + h * 8;
            float4 ka = *(const float4*)Kr;
            float4 kb = *(const float4*)(Kr + 4);
            float s = qa.x*ka.x + qa.y*ka.y + qa.z*ka.z + qa.w*ka.w
                    + qb.x*kb.x + qb.y*kb.y + qb.z*kb.z + qb.w*kb.w;
            if (mch[ql * MPAD + k]) s = MASK_FILL;
            float mn   = fmaxf(m, s);
            float corr = exp2f(m - mn);   // first iter: exp2(-inf)=0
            float p    = exp2f(s - mn);
            m = mn;
            l = l * corr + p;
            const float* Vr = Vch + k * 32 + h * 8;
            float4 va = *(const float4*)Vr;
            float4 vb = *(const float4*)(Vr + 4);
            c0 = c0*corr + p*va.x;  c1 = c1*corr + p*va.y;
            c2 = c2*corr + p*va.z;  c3 = c3*corr + p*va.w;
            c4 = c4*corr + p*vb.x;  c5 = c5*corr + p*vb.y;
            c6 = c6*corr + p*vb.z;  c7 = c7*corr + p*vb.w;
        }
        __syncthreads();
    }
    float inv = 1.0f / l;
    float4 o0 = make_float4(c0*inv, c1*inv, c2*inv, c3*inv);
    float4 o1 = make_float4(c4*inv, c5*inv, c6*inv, c7*inv);
    *(float4*)(sa_out + qrow * 32 + h * 8)     = o0;
    *(float4*)(sa_out + qrow * 32 + h * 8 + 4) = o1;
}

// ---------------------------------------------------------------------------
// Epilogue: y = sa @ W_O + b_O + residual; out = layernorm(y) (biased var).
__global__ __launch_bounds__(256) void epilogue_kernel(
    const float* __restrict__ sa, const float* __restrict__ WO,
    const float* __restrict__ bO, const float* __restrict__ resid,
    float* __restrict__ out0)
{
    __shared__ float sas[8][32];
    __shared__ float Ws[32][32];
    int t = threadIdx.x;
    long base = (long)blockIdx.x * 256;
    sas[t >> 5][t & 31] = sa[base + t];
#pragma unroll
    for (int i = 0; i < 4; ++i) {
        int f = i * 256 + t;
        Ws[f >> 5][f & 31] = WO[f];
    }
    __syncthreads();
    int r = t >> 5, j = t & 31;
    float y = bO[j] + resid[base + t];
#pragma unroll
    for (int i = 0; i < 32; ++i) y = fmaf(sas[r][i], Ws[i][j], y);

    float sum = y;
#pragma unroll
    for (int o = 16; o >= 1; o >>= 1) sum += __shfl_xor(sum, o, 32);
    float mu = sum * (1.0f / 32.0f);
    float d  = y - mu;
    float sq = d * d;
#pragma unroll
    for (int o = 16; o >= 1; o >>= 1) sq += __shfl_xor(sq, o, 32);
    float var = sq * (1.0f / 32.0f);
    out0[base + t] = d * rsqrtf(var + LN_EPS);
}

// ---------------------------------------------------------------------------
extern "C" void kernel_launch(void* const* d_in, const int* in_sizes, int n_in,
                              void* d_out, int out_size, void* d_ws, size_t ws_size,
                              hipStream_t stream)
{
    const float* inQ = (const float*)d_in[0];
    const float* inK = (const float*)d_in[1];
    const float* inV = (const float*)d_in[2];
    const void*  mask = d_in[3];
    const float* WQ = (const float*)d_in[4];
    const float* bQ = (const float*)d_in[5];
    const float* WK = (const float*)d_in[6];
    const float* bK = (const float*)d_in[7];
    const float* WV = (const float*)d_in[8];
    const float* bV = (const float*)d_in[9];
    const float* WO = (const float*)d_in[10];
    const float* bO = (const float*)d_in[11];

    const long NTOK = (long)B_SZ * S_LEN;          // 16384 rows
    float* out0 = (float*)d_out;                   // layernorm output
    float* sa   = (float*)d_out + NTOK * D_MODEL;  // self_attn output

    char* ws   = (char*)d_ws;
    int*  flag = (int*)ws;
    float* Qs  = (float*)(ws + 256);
    float* Ks  = Qs + NTOK * D_MODEL;
    float* Vs  = Ks + NTOK * D_MODEL;

    detect_mask_dtype<<<1, 64, 0, stream>>>((const unsigned char*)mask, flag);
    proj_kernel<<<dim3((int)(NTOK / 8), 3), 256, 0, stream>>>(
        inQ, inK, inV, WQ, bQ, WK, bK, WV, bV, Qs, Ks, Vs);
    attn_kernel<<<B_SZ * (S_LEN / QT), 64, 0, stream>>>(Qs, Ks, Vs, mask, flag, sa);
    epilogue_kernel<<<(int)(NTOK * D_MODEL / 256), 256, 0, stream>>>(
        sa, WO, bO, inQ, out0);
}

// Round 2
// 312.738 us; speedup vs baseline: 1.3294x; 1.3294x over previous
//
#include <hip/hip_runtime.h>
#include <hip/hip_bf16.h>
#include <math.h>

#define D_MODEL 32
#define N_HEADS 4
#define S_LEN   2048
#define B_SZ    8
#define NTOK    (B_SZ * S_LEN)
#define LN_EPS  1e-5f
#define LOG2E   1.44269504088896340736f
#define QK_SCALE 0.35355339059327373f   /* 1/sqrt(8) */
#define MASKV   (-1.0e9f * LOG2E)       /* mask fill in exp2 domain */

// ---------------------------------------------------------------------------
__global__ void detect_mask_dtype(const unsigned char* __restrict__ mb,
                                  int* __restrict__ flag) {
    int t = threadIdx.x;  // 64 lanes
    unsigned char b1 = mb[t * 4 + 1];
    unsigned char b2 = mb[t * 4 + 2];
    unsigned char b3 = mb[t * 4 + 3];
    int ok = ((b1 | b2 | b3) == 0);
    unsigned long long vote = __ballot(ok);
    if (t == 0) flag[0] = (vote == ~0ULL) ? 1 : 0;   // 1 => int32 layout
}

// ---------------------------------------------------------------------------
// QKV projection: out = (x @ W + b) * scale.  Q gets 1/sqrt(8)*log2e folded in.
__global__ __launch_bounds__(256) void proj_kernel(
    const float* __restrict__ xQ, const float* __restrict__ xK,
    const float* __restrict__ xV,
    const float* __restrict__ WQ, const float* __restrict__ bQ,
    const float* __restrict__ WK, const float* __restrict__ bK,
    const float* __restrict__ WV, const float* __restrict__ bV,
    float* __restrict__ Qs, float* __restrict__ Ks, float* __restrict__ Vs)
{
    const float* x; const float* W; const float* bias; float* dst; float scale;
    if (blockIdx.y == 0)      { x = xQ; W = WQ; bias = bQ; dst = Qs; scale = QK_SCALE * LOG2E; }
    else if (blockIdx.y == 1) { x = xK; W = WK; bias = bK; dst = Ks; scale = 1.0f; }
    else                      { x = xV; W = WV; bias = bV; dst = Vs; scale = 1.0f; }

    __shared__ float xs[8][32];
    __shared__ float Ws[32][32];
    int t = threadIdx.x;
    long base = (long)blockIdx.x * 256;    // 8 rows x 32 cols
    xs[t >> 5][t & 31] = x[base + t];
#pragma unroll
    for (int i = 0; i < 4; ++i) {
        int f = i * 256 + t;
        Ws[f >> 5][f & 31] = W[f];
    }
    __syncthreads();
    int r = t >> 5, j = t & 31;
    float acc = bias[j];
#pragma unroll
    for (int i = 0; i < 32; ++i) acc = fmaf(xs[r][i], Ws[i][j], acc);
    dst[base + t] = acc * scale;
}

// ---------------------------------------------------------------------------
// Split-K flash attention. Block = 1 wave; thread t -> (q = q0 + t/4, h = t&3).
// Covers keys [seg*SEGLEN, (seg+1)*SEGLEN). No LDS, no barriers: K/V served
// from L2 (XCD swizzle maps each batch to one XCD). 16-key chunks break the
// softmax dependency chain: 16 indep dots -> tree max -> 16 indep exp2 ->
// 8 indep PV chains -> one rescale per chunk.
template<int NSEG>
__global__ __launch_bounds__(64, 4) void attn_kernel(
    const float* __restrict__ Qs, const float* __restrict__ Ks,
    const float* __restrict__ Vs, const void* __restrict__ mask,
    const int* __restrict__ flag_p,
    float* __restrict__ pm, float* __restrict__ pl, float* __restrict__ pctx)
{
    constexpr int SEGLEN = S_LEN / NSEG;
    const int nb = NSEG * 128;                  // blocks per batch
    int raw = blockIdx.x;
    int cid = (raw & 7) * nb + (raw >> 3);      // XCD-contiguous (grid = 8*nb)
    int b   = cid / nb;
    int rem = cid - b * nb;
    int seg = rem >> 7;
    int qt  = rem & 127;

    int t  = threadIdx.x;
    int ql = t >> 2, h = t & 3;
    long tok = (long)b * S_LEN + qt * 16 + ql;

    float4 qa = *(const float4*)(Qs + tok * 32 + h * 8);
    float4 qb = *(const float4*)(Qs + tok * 32 + h * 8 + 4);

    int is_i32 = flag_p[0];
    const int* m32          = (const int*)mask;
    const unsigned char* m8 = (const unsigned char*)mask;
    long mrow = tok * S_LEN;

    const float* Kb = Ks + (long)b * S_LEN * 32;
    const float* Vb = Vs + (long)b * S_LEN * 32;

    float m = -INFINITY, l = 0.f;
    float c0=0,c1=0,c2=0,c3=0,c4=0,c5=0,c6=0,c7=0;

    int k0 = seg * SEGLEN;
#pragma unroll 1
    for (int kc = k0; kc < k0 + SEGLEN; kc += 16) {
        // ---- mask chunk: 16 ints
        int mm[16];
        if (is_i32) {
            const int4* mp = (const int4*)(m32 + mrow + kc);
            int4 a = mp[0], e = mp[1], f = mp[2], g = mp[3];
            mm[0]=a.x; mm[1]=a.y; mm[2]=a.z; mm[3]=a.w;
            mm[4]=e.x; mm[5]=e.y; mm[6]=e.z; mm[7]=e.w;
            mm[8]=f.x; mm[9]=f.y; mm[10]=f.z; mm[11]=f.w;
            mm[12]=g.x; mm[13]=g.y; mm[14]=g.z; mm[15]=g.w;
        } else {
            int4 v = *(const int4*)(m8 + mrow + kc);
            int w0=v.x, w1=v.y, w2=v.z, w3=v.w;
            mm[0]=w0&255; mm[1]=(w0>>8)&255; mm[2]=(w0>>16)&255; mm[3]=(w0>>24)&255;
            mm[4]=w1&255; mm[5]=(w1>>8)&255; mm[6]=(w1>>16)&255; mm[7]=(w1>>24)&255;
            mm[8]=w2&255; mm[9]=(w2>>8)&255; mm[10]=(w2>>16)&255; mm[11]=(w2>>24)&255;
            mm[12]=w3&255; mm[13]=(w3>>8)&255; mm[14]=(w3>>16)&255; mm[15]=(w3>>24)&255;
        }
        // ---- 16 independent scores
        float s[16];
#pragma unroll
        for (int k = 0; k < 16; ++k) {
            const float4* Kr = (const float4*)(Kb + (long)(kc + k) * 32 + h * 8);
            float4 ka = Kr[0], kb2 = Kr[1];
            float d = qa.x*ka.x + qa.y*ka.y + qa.z*ka.z + qa.w*ka.w
                    + qb.x*kb2.x + qb.y*kb2.y + qb.z*kb2.z + qb.w*kb2.w;
            s[k] = mm[k] ? MASKV : d;
        }
        // ---- tree max (depth 4)
        float x0 = fmaxf(s[0], s[8]),  x1 = fmaxf(s[1], s[9]);
        float x2 = fmaxf(s[2], s[10]), x3 = fmaxf(s[3], s[11]);
        float x4 = fmaxf(s[4], s[12]), x5 = fmaxf(s[5], s[13]);
        float x6 = fmaxf(s[6], s[14]), x7 = fmaxf(s[7], s[15]);
        x0 = fmaxf(x0, x4); x1 = fmaxf(x1, x5);
        x2 = fmaxf(x2, x6); x3 = fmaxf(x3, x7);
        x0 = fmaxf(x0, x2); x1 = fmaxf(x1, x3);
        float mc = fmaxf(x0, x1);
        // ---- 16 indep exp2, 8 indep PV chains, 2-way l partial sums
        float d0=0,d1=0,d2=0,d3=0,d4=0,d5=0,d6=0,d7=0;
        float ls0 = 0.f, ls1 = 0.f;
#pragma unroll
        for (int k = 0; k < 16; ++k) {
            float pk = exp2f(s[k] - mc);
            if (k & 1) ls1 += pk; else ls0 += pk;
            const float4* Vr = (const float4*)(Vb + (long)(kc + k) * 32 + h * 8);
            float4 va = Vr[0], vb2 = Vr[1];
            d0 = fmaf(pk, va.x, d0);  d1 = fmaf(pk, va.y, d1);
            d2 = fmaf(pk, va.z, d2);  d3 = fmaf(pk, va.w, d3);
            d4 = fmaf(pk, vb2.x, d4); d5 = fmaf(pk, vb2.y, d5);
            d6 = fmaf(pk, vb2.z, d6); d7 = fmaf(pk, vb2.w, d7);
        }
        // ---- one rescale per chunk
        float mn   = fmaxf(m, mc);
        float corr = exp2f(m - mn);
        float cc   = exp2f(mc - mn);
        m = mn;
        l  = l  * corr + (ls0 + ls1) * cc;
        c0 = c0 * corr + d0 * cc;  c1 = c1 * corr + d1 * cc;
        c2 = c2 * corr + d2 * cc;  c3 = c3 * corr + d3 * cc;
        c4 = c4 * corr + d4 * cc;  c5 = c5 * corr + d5 * cc;
        c6 = c6 * corr + d6 * cc;  c7 = c7 * corr + d7 * cc;
    }
    long pidx = ((long)seg * NTOK + tok) * 4 + h;
    pm[pidx] = m;
    pl[pidx] = l;
    float* pc = pctx + ((long)seg * NTOK + tok) * 32 + h * 8;
    *(float4*)(pc)     = make_float4(c0, c1, c2, c3);
    *(float4*)(pc + 4) = make_float4(c4, c5, c6, c7);
}

// ---------------------------------------------------------------------------
// Merge split-K partials -> sa; then attn_output = sa@WO + bO + resid; LN.
template<int NSEG>
__global__ __launch_bounds__(256) void combine_epilogue(
    const float* __restrict__ pm, const float* __restrict__ pl,
    const float* __restrict__ pctx, const float* __restrict__ WO,
    const float* __restrict__ bO, const float* __restrict__ resid,
    float* __restrict__ sa_out, float* __restrict__ out0)
{
    __shared__ float sas[8][32];
    __shared__ float Ws[32][32];
    int t = threadIdx.x;
    long base = (long)blockIdx.x * 256;      // 8 tokens x 32
    int r = t >> 5, j = t & 31;
    long tok = (long)blockIdx.x * 8 + r;
    int h = j >> 3;

#pragma unroll
    for (int i = 0; i < 4; ++i) {
        int f = i * 256 + t;
        Ws[f >> 5][f & 31] = WO[f];
    }

    float ms[NSEG];
#pragma unroll
    for (int s2 = 0; s2 < NSEG; ++s2)
        ms[s2] = pm[((long)s2 * NTOK + tok) * 4 + h];
    float M = ms[0];
#pragma unroll
    for (int s2 = 1; s2 < NSEG; ++s2) M = fmaxf(M, ms[s2]);

    float L = 0.f, ctx = 0.f;
#pragma unroll
    for (int s2 = 0; s2 < NSEG; ++s2) {
        float w = exp2f(ms[s2] - M);
        L   = fmaf(pl[((long)s2 * NTOK + tok) * 4 + h], w, L);
        ctx = fmaf(pctx[((long)s2 * NTOK + tok) * 32 + j], w, ctx);
    }
    float sa = ctx / L;
    sa_out[base + t] = sa;
    sas[r][j] = sa;
    __syncthreads();

    float y = bO[j] + resid[base + t];
#pragma unroll
    for (int i = 0; i < 32; ++i) y = fmaf(sas[r][i], Ws[i][j], y);

    float sum = y;
#pragma unroll
    for (int o = 16; o >= 1; o >>= 1) sum += __shfl_xor(sum, o, 32);
    float mu = sum * (1.0f / 32.0f);
    float d  = y - mu;
    float sq = d * d;
#pragma unroll
    for (int o = 16; o >= 1; o >>= 1) sq += __shfl_xor(sq, o, 32);
    float var = sq * (1.0f / 32.0f);
    out0[base + t] = d * rsqrtf(var + LN_EPS);
}

// ---------------------------------------------------------------------------
extern "C" void kernel_launch(void* const* d_in, const int* in_sizes, int n_in,
                              void* d_out, int out_size, void* d_ws, size_t ws_size,
                              hipStream_t stream)
{
    const float* inQ = (const float*)d_in[0];
    const float* inK = (const float*)d_in[1];
    const float* inV = (const float*)d_in[2];
    const void*  mask = d_in[3];
    const float* WQ = (const float*)d_in[4];
    const float* bQ = (const float*)d_in[5];
    const float* WK = (const float*)d_in[6];
    const float* bK = (const float*)d_in[7];
    const float* WV = (const float*)d_in[8];
    const float* bV = (const float*)d_in[9];
    const float* WO = (const float*)d_in[10];
    const float* bO = (const float*)d_in[11];

    float* out0 = (float*)d_out;                    // layernorm output
    float* sa   = (float*)d_out + (long)NTOK * 32;  // self_attn output

    char* ws   = (char*)d_ws;
    int*  flag = (int*)ws;
    float* Qs  = (float*)(ws + 256);
    float* Ks  = Qs + (long)NTOK * 32;
    float* Vs  = Ks + (long)NTOK * 32;
    float* pbase = Vs + (long)NTOK * 32;

    // pick NSEG by available workspace: per-seg = pm+pl+pctx = NTOK*(4+4+32)*4 B
    size_t fixed  = 256 + 3ul * NTOK * 32 * 4;
    size_t perseg = (size_t)NTOK * 40 * 4;
    int NS = 1;
    if      (fixed + 8 * perseg <= ws_size) NS = 8;
    else if (fixed + 4 * perseg <= ws_size) NS = 4;
    else if (fixed + 2 * perseg <= ws_size) NS = 2;

    float* pm   = pbase;
    float* pl   = pm + (long)NS * NTOK * 4;
    float* pctx = pl + (long)NS * NTOK * 4;

    detect_mask_dtype<<<1, 64, 0, stream>>>((const unsigned char*)mask, flag);
    proj_kernel<<<dim3(NTOK / 8, 3), 256, 0, stream>>>(
        inQ, inK, inV, WQ, bQ, WK, bK, WV, bV, Qs, Ks, Vs);

    int agrid = B_SZ * NS * 128;
    int cgrid = NTOK / 8;
    switch (NS) {
    case 8:
        attn_kernel<8><<<agrid, 64, 0, stream>>>(Qs, Ks, Vs, mask, flag, pm, pl, pctx);
        combine_epilogue<8><<<cgrid, 256, 0, stream>>>(pm, pl, pctx, WO, bO, inQ, sa, out0);
        break;
    case 4:
        attn_kernel<4><<<agrid, 64, 0, stream>>>(Qs, Ks, Vs, mask, flag, pm, pl, pctx);
        combine_epilogue<4><<<cgrid, 256, 0, stream>>>(pm, pl, pctx, WO, bO, inQ, sa, out0);
        break;
    case 2:
        attn_kernel<2><<<agrid, 64, 0, stream>>>(Qs, Ks, Vs, mask, flag, pm, pl, pctx);
        combine_epilogue<2><<<cgrid, 256, 0, stream>>>(pm, pl, pctx, WO, bO, inQ, sa, out0);
        break;
    default:
        attn_kernel<1><<<agrid, 64, 0, stream>>>(Qs, Ks, Vs, mask, flag, pm, pl, pctx);
        combine_epilogue<1><<<cgrid, 256, 0, stream>>>(pm, pl, pctx, WO, bO, inQ, sa, out0);
        break;
    }
}

// Round 3
// 148.093 us; speedup vs baseline: 2.8073x; 2.1118x over previous
//
#include <hip/hip_runtime.h>
#include <hip/hip_bf16.h>
#include <math.h>

#define D_MODEL 32
#define N_HEADS 4
#define S_LEN   2048
#define B_SZ    8
#define NTOK    (B_SZ * S_LEN)
#define LN_EPS  1e-5f
#define LOG2E   1.44269504088896340736f
#define QK_SCALE 0.35355339059327373f   /* 1/sqrt(8) */
#define MASKV   (-1.0e9f * LOG2E)       /* mask fill in exp2 domain */
#define CK      16                       /* keys per chunk */

typedef const __attribute__((address_space(1))) void* gp_t;
typedef __attribute__((address_space(3))) void* sp_t;

__device__ __forceinline__ void dma16(const void* g, void* s) {
    __builtin_amdgcn_global_load_lds((gp_t)g, (sp_t)s, 16, 0, 0);
}
__device__ __forceinline__ void dma4(const void* g, void* s) {
    __builtin_amdgcn_global_load_lds((gp_t)g, (sp_t)s, 4, 0, 0);
}

// ---------------------------------------------------------------------------
__global__ void detect_mask_dtype(const unsigned char* __restrict__ mb,
                                  int* __restrict__ flag) {
    int t = threadIdx.x;  // 64 lanes
    unsigned char b1 = mb[t * 4 + 1];
    unsigned char b2 = mb[t * 4 + 2];
    unsigned char b3 = mb[t * 4 + 3];
    int ok = ((b1 | b2 | b3) == 0);
    unsigned long long vote = __ballot(ok);
    if (t == 0) flag[0] = (vote == ~0ULL) ? 1 : 0;   // 1 => int32 layout
}

// ---------------------------------------------------------------------------
// QKV projection: out = (x @ W + b) * scale.  Q gets 1/sqrt(8)*log2e folded in.
__global__ __launch_bounds__(256) void proj_kernel(
    const float* __restrict__ xQ, const float* __restrict__ xK,
    const float* __restrict__ xV,
    const float* __restrict__ WQ, const float* __restrict__ bQ,
    const float* __restrict__ WK, const float* __restrict__ bK,
    const float* __restrict__ WV, const float* __restrict__ bV,
    float* __restrict__ Qs, float* __restrict__ Ks, float* __restrict__ Vs)
{
    const float* x; const float* W; const float* bias; float* dst; float scale;
    if (blockIdx.y == 0)      { x = xQ; W = WQ; bias = bQ; dst = Qs; scale = QK_SCALE * LOG2E; }
    else if (blockIdx.y == 1) { x = xK; W = WK; bias = bK; dst = Ks; scale = 1.0f; }
    else                      { x = xV; W = WV; bias = bV; dst = Vs; scale = 1.0f; }

    __shared__ float xs[8][32];
    __shared__ float Ws[32][32];
    int t = threadIdx.x;
    long base = (long)blockIdx.x * 256;    // 8 rows x 32 cols
    xs[t >> 5][t & 31] = x[base + t];
#pragma unroll
    for (int i = 0; i < 4; ++i) {
        int f = i * 256 + t;
        Ws[f >> 5][f & 31] = W[f];
    }
    __syncthreads();
    int r = t >> 5, j = t & 31;
    float acc = bias[j];
#pragma unroll
    for (int i = 0; i < 32; ++i) acc = fmaf(xs[r][i], Ws[i][j], acc);
    dst[base + t] = acc * scale;
}

// ---------------------------------------------------------------------------
// Split-K flash attention, LDS-DMA pipelined. 1 wave per block, no barriers.
// thread t -> (q = qt*16 + t/4, h = t&3). K/V/mask staged double-buffered via
// global_load_lds with counted vmcnt waits; mask DMA'd TRANSPOSED so the
// per-key ds_read_b32 is bank-conflict-free.
template<int NSEG, bool I32>
__device__ __forceinline__ void attn_body(
    int lane, int b, int seg, int qt,
    const float* __restrict__ Qs, const float* __restrict__ Kb,
    const float* __restrict__ Vb, const void* __restrict__ mask,
    float* __restrict__ pm, float* __restrict__ pl, float* __restrict__ pctx,
    float (*Kl)[CK * 32], float (*Vl)[CK * 32], int (*Ml)[CK * 16])
{
    constexpr int SEGLEN = S_LEN / NSEG;
    constexpr int NCH    = SEGLEN / CK;
    int ql = lane >> 2, h = lane & 3;
    int tok0 = qt * 16;                              // within batch
    long tok = (long)b * S_LEN + tok0 + ql;
    int k0 = seg * SEGLEN;

    float4 qa = *(const float4*)(Qs + tok * 32 + h * 8);
    float4 qb = *(const float4*)(Qs + tok * 32 + h * 8 + 4);

    const char* kg = (const char*)Kb + (size_t)k0 * 128 + lane * 16;
    const char* vg = (const char*)Vb + (size_t)k0 * 128 + lane * 16;
    const char* mg = nullptr;
    const unsigned char* m8row = nullptr;
    if (I32) {
        const int* m32 = (const int*)mask;
        // transposed DMA: LDS int n = k*16 + r; instr j, lane i -> k = j*4+(i>>4), r = i&15
        mg = (const char*)(m32 + ((size_t)b * S_LEN + tok0 + (lane & 15)) * S_LEN
                               + k0 + (lane >> 4));
    } else {
        m8row = (const unsigned char*)mask + (size_t)tok * S_LEN + k0;
    }

    // prologue: stage chunk 0 into buffer 0
    dma16(kg, &Kl[0][0]); dma16(kg + 1024, &Kl[0][256]);
    dma16(vg, &Vl[0][0]); dma16(vg + 1024, &Vl[0][256]);
    if (I32) {
        dma4(mg,      &Ml[0][0]);   dma4(mg + 16, &Ml[0][64]);
        dma4(mg + 32, &Ml[0][128]); dma4(mg + 48, &Ml[0][192]);
    }
    kg += CK * 128; vg += CK * 128; if (I32) mg += CK * 4;

    float m = -INFINITY, l = 0.f;
    float c0=0,c1=0,c2=0,c3=0,c4=0,c5=0,c6=0,c7=0;

#pragma unroll 1
    for (int c = 0; c < NCH; ++c) {
        int cur = c & 1, nxt = cur ^ 1;
        if (c + 1 < NCH) {
            dma16(kg, &Kl[nxt][0]); dma16(kg + 1024, &Kl[nxt][256]);
            dma16(vg, &Vl[nxt][0]); dma16(vg + 1024, &Vl[nxt][256]);
            if (I32) {
                dma4(mg,      &Ml[nxt][0]);   dma4(mg + 16, &Ml[nxt][64]);
                dma4(mg + 32, &Ml[nxt][128]); dma4(mg + 48, &Ml[nxt][192]);
                kg += CK * 128; vg += CK * 128; mg += CK * 4;
                asm volatile("s_waitcnt vmcnt(8)" ::: "memory");
            } else {
                kg += CK * 128; vg += CK * 128;
                asm volatile("s_waitcnt vmcnt(0)" ::: "memory");
            }
        } else {
            asm volatile("s_waitcnt vmcnt(0)" ::: "memory");
        }

        const float* Kc = &Kl[cur][0] + h * 8;
        const float* Vc = &Vl[cur][0] + h * 8;
        const int*   Mq = &Ml[cur][0] + ql;

        float s[CK];
        if (I32) {
#pragma unroll
            for (int k = 0; k < CK; ++k) {
                float4 ka = *(const float4*)(Kc + k * 32);
                float4 k2 = *(const float4*)(Kc + k * 32 + 4);
                float d = qa.x*ka.x + qa.y*ka.y + qa.z*ka.z + qa.w*ka.w
                        + qb.x*k2.x + qb.y*k2.y + qb.z*k2.z + qb.w*k2.w;
                s[k] = Mq[k * 16] ? MASKV : d;
            }
        } else {
            int4 mv = *(const int4*)(m8row + (size_t)c * CK);
            int mw[4] = {mv.x, mv.y, mv.z, mv.w};
#pragma unroll
            for (int k = 0; k < CK; ++k) {
                float4 ka = *(const float4*)(Kc + k * 32);
                float4 k2 = *(const float4*)(Kc + k * 32 + 4);
                float d = qa.x*ka.x + qa.y*ka.y + qa.z*ka.z + qa.w*ka.w
                        + qb.x*k2.x + qb.y*k2.y + qb.z*k2.z + qb.w*k2.w;
                int mk = (mw[k >> 2] >> ((k & 3) * 8)) & 255;
                s[k] = mk ? MASKV : d;
            }
        }

        // tree max (depth 4)
        float x0 = fmaxf(s[0], s[8]),  x1 = fmaxf(s[1], s[9]);
        float x2 = fmaxf(s[2], s[10]), x3 = fmaxf(s[3], s[11]);
        float x4 = fmaxf(s[4], s[12]), x5 = fmaxf(s[5], s[13]);
        float x6 = fmaxf(s[6], s[14]), x7 = fmaxf(s[7], s[15]);
        x0 = fmaxf(x0, x4); x1 = fmaxf(x1, x5);
        x2 = fmaxf(x2, x6); x3 = fmaxf(x3, x7);
        x0 = fmaxf(x0, x2); x1 = fmaxf(x1, x3);
        float mc = fmaxf(x0, x1);

        float d0=0,d1=0,d2=0,d3=0,d4=0,d5=0,d6=0,d7=0;
        float ls0 = 0.f, ls1 = 0.f;
#pragma unroll
        for (int k = 0; k < CK; ++k) {
            float pk = exp2f(s[k] - mc);
            if (k & 1) ls1 += pk; else ls0 += pk;
            float4 va = *(const float4*)(Vc + k * 32);
            float4 v2 = *(const float4*)(Vc + k * 32 + 4);
            d0 = fmaf(pk, va.x, d0);  d1 = fmaf(pk, va.y, d1);
            d2 = fmaf(pk, va.z, d2);  d3 = fmaf(pk, va.w, d3);
            d4 = fmaf(pk, v2.x, d4);  d5 = fmaf(pk, v2.y, d5);
            d6 = fmaf(pk, v2.z, d6);  d7 = fmaf(pk, v2.w, d7);
        }

        float mn   = fmaxf(m, mc);
        float corr = exp2f(m - mn);
        float cc   = exp2f(mc - mn);
        m = mn;
        l  = l  * corr + (ls0 + ls1) * cc;
        c0 = c0 * corr + d0 * cc;  c1 = c1 * corr + d1 * cc;
        c2 = c2 * corr + d2 * cc;  c3 = c3 * corr + d3 * cc;
        c4 = c4 * corr + d4 * cc;  c5 = c5 * corr + d5 * cc;
        c6 = c6 * corr + d6 * cc;  c7 = c7 * corr + d7 * cc;
    }

    long pidx = ((long)seg * NTOK + tok) * 4 + h;
    pm[pidx] = m;
    pl[pidx] = l;
    float* pc = pctx + ((long)seg * NTOK + tok) * 32 + h * 8;
    *(float4*)(pc)     = make_float4(c0, c1, c2, c3);
    *(float4*)(pc + 4) = make_float4(c4, c5, c6, c7);
}

template<int NSEG>
__global__ __launch_bounds__(64) void attn_kernel(
    const float* __restrict__ Qs, const float* __restrict__ Ks,
    const float* __restrict__ Vs, const void* __restrict__ mask,
    const int* __restrict__ flag_p,
    float* __restrict__ pm, float* __restrict__ pl, float* __restrict__ pctx)
{
    __shared__ float Kl[2][CK * 32];
    __shared__ float Vl[2][CK * 32];
    __shared__ int   Ml[2][CK * 16];

    const int nb = NSEG * 128;                  // blocks per batch
    int raw = blockIdx.x;
    int cid = (raw & 7) * nb + (raw >> 3);      // XCD-contiguous (grid = 8*nb)
    int b   = cid / nb;
    int rem = cid - b * nb;
    int seg = rem >> 7;
    int qt  = rem & 127;
    int lane = threadIdx.x;

    const float* Kb = Ks + (long)b * S_LEN * 32;
    const float* Vb = Vs + (long)b * S_LEN * 32;

    if (flag_p[0])
        attn_body<NSEG, true >(lane, b, seg, qt, Qs, Kb, Vb, mask, pm, pl, pctx, Kl, Vl, Ml);
    else
        attn_body<NSEG, false>(lane, b, seg, qt, Qs, Kb, Vb, mask, pm, pl, pctx, Kl, Vl, Ml);
}

// ---------------------------------------------------------------------------
// Merge split-K partials -> sa; then attn_output = sa@WO + bO + resid; LN.
template<int NSEG>
__global__ __launch_bounds__(256) void combine_epilogue(
    const float* __restrict__ pm, const float* __restrict__ pl,
    const float* __restrict__ pctx, const float* __restrict__ WO,
    const float* __restrict__ bO, const float* __restrict__ resid,
    float* __restrict__ sa_out, float* __restrict__ out0)
{
    __shared__ float sas[8][32];
    __shared__ float Ws[32][32];
    int t = threadIdx.x;
    long base = (long)blockIdx.x * 256;      // 8 tokens x 32
    int r = t >> 5, j = t & 31;
    long tok = (long)blockIdx.x * 8 + r;
    int h = j >> 3;

#pragma unroll
    for (int i = 0; i < 4; ++i) {
        int f = i * 256 + t;
        Ws[f >> 5][f & 31] = WO[f];
    }

    float ms[NSEG];
#pragma unroll
    for (int s2 = 0; s2 < NSEG; ++s2)
        ms[s2] = pm[((long)s2 * NTOK + tok) * 4 + h];
    float M = ms[0];
#pragma unroll
    for (int s2 = 1; s2 < NSEG; ++s2) M = fmaxf(M, ms[s2]);

    float L = 0.f, ctx = 0.f;
#pragma unroll
    for (int s2 = 0; s2 < NSEG; ++s2) {
        float w = exp2f(ms[s2] - M);
        L   = fmaf(pl[((long)s2 * NTOK + tok) * 4 + h], w, L);
        ctx = fmaf(pctx[((long)s2 * NTOK + tok) * 32 + j], w, ctx);
    }
    float sa = ctx / L;
    sa_out[base + t] = sa;
    sas[r][j] = sa;
    __syncthreads();

    float y = bO[j] + resid[base + t];
#pragma unroll
    for (int i = 0; i < 32; ++i) y = fmaf(sas[r][i], Ws[i][j], y);

    float sum = y;
#pragma unroll
    for (int o = 16; o >= 1; o >>= 1) sum += __shfl_xor(sum, o, 32);
    float mu = sum * (1.0f / 32.0f);
    float d  = y - mu;
    float sq = d * d;
#pragma unroll
    for (int o = 16; o >= 1; o >>= 1) sq += __shfl_xor(sq, o, 32);
    float var = sq * (1.0f / 32.0f);
    out0[base + t] = d * rsqrtf(var + LN_EPS);
}

// ---------------------------------------------------------------------------
extern "C" void kernel_launch(void* const* d_in, const int* in_sizes, int n_in,
                              void* d_out, int out_size, void* d_ws, size_t ws_size,
                              hipStream_t stream)
{
    const float* inQ = (const float*)d_in[0];
    const float* inK = (const float*)d_in[1];
    const float* inV = (const float*)d_in[2];
    const void*  mask = d_in[3];
    const float* WQ = (const float*)d_in[4];
    const float* bQ = (const float*)d_in[5];
    const float* WK = (const float*)d_in[6];
    const float* bK = (const float*)d_in[7];
    const float* WV = (const float*)d_in[8];
    const float* bV = (const float*)d_in[9];
    const float* WO = (const float*)d_in[10];
    const float* bO = (const float*)d_in[11];

    float* out0 = (float*)d_out;                    // layernorm output
    float* sa   = (float*)d_out + (long)NTOK * 32;  // self_attn output

    char* ws   = (char*)d_ws;
    int*  flag = (int*)ws;
    float* Qs  = (float*)(ws + 256);
    float* Ks  = Qs + (long)NTOK * 32;
    float* Vs  = Ks + (long)NTOK * 32;
    float* pbase = Vs + (long)NTOK * 32;

    // pick NSEG by available workspace: per-seg = pm+pl+pctx = NTOK*(4+4+32)*4 B
    size_t fixed  = 256 + 3ul * NTOK * 32 * 4;
    size_t perseg = (size_t)NTOK * 40 * 4;
    int NS = 1;
    if      (fixed + 8 * perseg <= ws_size) NS = 8;
    else if (fixed + 4 * perseg <= ws_size) NS = 4;
    else if (fixed + 2 * perseg <= ws_size) NS = 2;

    float* pm   = pbase;
    float* pl   = pm + (long)NS * NTOK * 4;
    float* pctx = pl + (long)NS * NTOK * 4;

    detect_mask_dtype<<<1, 64, 0, stream>>>((const unsigned char*)mask, flag);
    proj_kernel<<<dim3(NTOK / 8, 3), 256, 0, stream>>>(
        inQ, inK, inV, WQ, bQ, WK, bK, WV, bV, Qs, Ks, Vs);

    int agrid = B_SZ * NS * 128;
    int cgrid = NTOK / 8;
    switch (NS) {
    case 8:
        attn_kernel<8><<<agrid, 64, 0, stream>>>(Qs, Ks, Vs, mask, flag, pm, pl, pctx);
        combine_epilogue<8><<<cgrid, 256, 0, stream>>>(pm, pl, pctx, WO, bO, inQ, sa, out0);
        break;
    case 4:
        attn_kernel<4><<<agrid, 64, 0, stream>>>(Qs, Ks, Vs, mask, flag, pm, pl, pctx);
        combine_epilogue<4><<<cgrid, 256, 0, stream>>>(pm, pl, pctx, WO, bO, inQ, sa, out0);
        break;
    case 2:
        attn_kernel<2><<<agrid, 64, 0, stream>>>(Qs, Ks, Vs, mask, flag, pm, pl, pctx);
        combine_epilogue<2><<<cgrid, 256, 0, stream>>>(pm, pl, pctx, WO, bO, inQ, sa, out0);
        break;
    default:
        attn_kernel<1><<<agrid, 64, 0, stream>>>(Qs, Ks, Vs, mask, flag, pm, pl, pctx);
        combine_epilogue<1><<<cgrid, 256, 0, stream>>>(pm, pl, pctx, WO, bO, inQ, sa, out0);
        break;
    }
}